// Round 1
// baseline (26845.862 us; speedup 1.0000x reference)
//
#include <hip/hip_runtime.h>
#include <math.h>

#define H    2048
#define V    50257
#define NS   128
#define EE   512
#define TT   64
#define PP   32
#define SS   16
#define RR   16
#define NSH  (NS*H)          // 262144
#define NEGV (-1e30f)

__device__ __forceinline__ float safelog(float x){
    return x > 0.0f ? logf(fmaxf(x, 1e-38f)) : NEGV;
}

// ---------- reductions over beta ----------
__global__ __launch_bounds__(256) void k_rowmax_beta(const float* beta, float* rm){
    int h = blockIdx.x;
    __shared__ float red[256];
    float m = -INFINITY;
    for (int v = threadIdx.x; v < V; v += 256) m = fmaxf(m, beta[(size_t)h*V + v]);
    red[threadIdx.x] = m; __syncthreads();
    for (int s = 128; s; s >>= 1){
        if (threadIdx.x < s) red[threadIdx.x] = fmaxf(red[threadIdx.x], red[threadIdx.x+s]);
        __syncthreads();
    }
    if (!threadIdx.x) rm[h] = red[0];
}

__global__ __launch_bounds__(256) void k_colmax_beta(const float* beta, float* bcm){
    int v = blockIdx.x*256 + threadIdx.x;
    if (v >= V) return;
    float m = -INFINITY;
    for (int h = 0; h < H; ++h) m = fmaxf(m, beta[(size_t)h*V + v]);
    bcm[v] = m;
}

// ---------- gather beta columns for tokens ----------
__global__ __launch_bounds__(256) void k_gather(const float* beta, const int* pre, const int* suf,
                                                float* bpre, float* bsuf){
    int i = blockIdx.y;
    int h = blockIdx.x*256 + threadIdx.x;
    if (h >= H) return;
    if (i < PP) bpre[(size_t)i*H + h] = beta[(size_t)h*V + pre[i]];
    else        bsuf[(size_t)(i-PP)*H + h] = beta[(size_t)h*V + suf[i-PP]];
}

__global__ __launch_bounds__(256) void k_copy(const float* src, float* dst, int n){
    int i = blockIdx.x*256 + threadIdx.x;
    if (i < n) dst[i] = src[i];
}

// ---------- A scan step: y' = matmul_loga_b((y+betacol)[None,:], alpha)[0] ----------
__global__ __launch_bounds__(256) void k_a_step(const float* yin, const float* bcol,
                                                const float* alpha, float* yout){
    __shared__ float sa[H];
    __shared__ float red[256];
    __shared__ float part[4][64];
    int tid = threadIdx.x;
    float m = -INFINITY;
    for (int j = tid; j < H; j += 256){ float a = yin[j] + bcol[j]; sa[j] = a; m = fmaxf(m, a); }
    red[tid] = m; __syncthreads();
    for (int s = 128; s; s >>= 1){ if (tid < s) red[tid] = fmaxf(red[tid], red[tid+s]); __syncthreads(); }
    float mm = red[0];
    __syncthreads();
    for (int j = tid; j < H; j += 256) sa[j] = expf(sa[j] - mm);
    __syncthreads();
    int lane = tid & 63, grp = tid >> 6;
    int j = blockIdx.x*64 + lane;
    float acc = 0.f;
    for (int h = grp*512; h < grp*512 + 512; ++h) acc += sa[h]*alpha[(size_t)h*H + j];
    part[grp][lane] = acc; __syncthreads();
    if (tid < 64){
        int jj = blockIdx.x*64 + tid;
        float s4 = part[0][tid] + part[1][tid] + part[2][tid] + part[3][tid];
        yout[jj] = safelog(s4) + mm;
    }
}

// ---------- B scan step: y' = matmul_a_logb(alpha, y[:,None])[:,0] + betacol ----------
__global__ __launch_bounds__(256) void k_b_step(const float* yin, const float* bcol,
                                                const float* alpha, float* yout){
    __shared__ float sy[H];
    __shared__ float red[256];
    int tid = threadIdx.x;
    float m = -INFINITY;
    for (int j = tid; j < H; j += 256){ float a = yin[j]; sy[j] = a; m = fmaxf(m, a); }
    red[tid] = m; __syncthreads();
    for (int s = 128; s; s >>= 1){ if (tid < s) red[tid] = fmaxf(red[tid], red[tid+s]); __syncthreads(); }
    float mm = red[0];
    __syncthreads();
    for (int j = tid; j < H; j += 256) sy[j] = expf(sy[j] - mm);
    __syncthreads();
    int lane = tid & 63, w = tid >> 6;
    int h = blockIdx.x*4 + w;
    float acc = 0.f;
    for (int j = lane; j < H; j += 64) acc += sy[j]*alpha[(size_t)h*H + j];
    for (int off = 32; off; off >>= 1) acc += __shfl_down(acc, off);
    if (!lane) yout[h] = safelog(acc) + mm + bcol[h];
}

// ---------- y0 = matmul_loga_b(where(accept, B0, NEG), alpha.T) -> C[0] ----------
__global__ __launch_bounds__(256) void k_y0(const float* B0, const float* alpha,
                                            const int* accept, float* C0){
    __shared__ float sb[H];
    __shared__ float red[256];
    __shared__ float pa[4][64], pb[4][64];
    int tid = threadIdx.x;
    float m = -INFINITY;
    for (int j = tid; j < H; j += 256){ float a = B0[j]; sb[j] = a; m = fmaxf(m, a); }
    red[tid] = m; __syncthreads();
    for (int s = 128; s; s >>= 1){ if (tid < s) red[tid] = fmaxf(red[tid], red[tid+s]); __syncthreads(); }
    float mm = red[0];
    __syncthreads();
    for (int j = tid; j < H; j += 256) sb[j] = expf(sb[j] - mm);
    __syncthreads();
    int lane = tid & 63, grp = tid >> 6;
    int j = blockIdx.x*64 + lane;
    const float4* arow = (const float4*)(alpha + (size_t)j*H);
    float sA = 0.f, sB = 0.f;
    for (int h4 = grp*128; h4 < grp*128 + 128; ++h4){
        float4 a4 = arow[h4];
        sA += sb[4*h4]*a4.x + sb[4*h4+1]*a4.y + sb[4*h4+2]*a4.z + sb[4*h4+3]*a4.w;
        sB += a4.x + a4.y + a4.z + a4.w;
    }
    pa[grp][lane] = sA; pb[grp][lane] = sB;
    __syncthreads();
    if (tid < 64){
        int jj = blockIdx.x*64 + tid;
        float SA = pa[0][tid]+pa[1][tid]+pa[2][tid]+pa[3][tid];
        float SB = pb[0][tid]+pb[1][tid]+pb[2][tid]+pb[3][tid];
        float la = safelog(SA) + mm;
        float lb = safelog(SB) + NEGV;
        for (int s = 0; s < NS; ++s) C0[(size_t)s*H + jj] = accept[s] ? la : lb;
    }
}

// ---------- T_weights big GEMM (split-K, atomic accumulate of linear sums) ----------
#define TKC 8
#define KSPLIT 3904
__global__ __launch_bounds__(256) void k_tw_gemm(const float* Tm, const float* beta,
                                                 const float* rm, float* Twsum){
    int bx = blockIdx.x;
    int et = bx & 3, ht = bx >> 2;          // e fastest for beta L2 reuse
    int e0 = et*128, h0 = ht*128;
    int k0 = blockIdx.y * KSPLIT;
    int kend = min(k0 + KSPLIT, V);
    __shared__ float AL[TKC][129];
    __shared__ float BL[TKC][129];
    int tid = threadIdx.x;
    int tx = tid & 15, ty = tid >> 4;       // h = 8*tx, e = 8*ty
    int r = tid >> 1, q = tid & 1;
    float rmh = rm[h0 + r];
    float acc[8][8] = {};
    for (int kc = k0; kc < kend; kc += TKC){
        int kb = kc + 4*q;
        #pragma unroll
        for (int i = 0; i < 4; ++i){
            int k = kb + i;
            float tv = 0.f, bv = 0.f;
            if (k < kend){
                tv = Tm[(size_t)(e0+r)*V + k];
                bv = expf(beta[(size_t)(h0+r)*V + k] - rmh);
            }
            AL[4*q+i][r] = tv;
            BL[4*q+i][r] = bv;
        }
        __syncthreads();
        #pragma unroll
        for (int kk = 0; kk < TKC; ++kk){
            float a[8], b[8];
            #pragma unroll
            for (int i = 0; i < 8; ++i) a[i] = AL[kk][8*ty+i];
            #pragma unroll
            for (int j = 0; j < 8; ++j) b[j] = BL[kk][8*tx+j];
            #pragma unroll
            for (int i = 0; i < 8; ++i)
                #pragma unroll
                for (int j = 0; j < 8; ++j) acc[i][j] += a[i]*b[j];
        }
        __syncthreads();
    }
    #pragma unroll
    for (int i = 0; i < 8; ++i)
        #pragma unroll
        for (int j = 0; j < 8; ++j)
            atomicAdd(&Twsum[(size_t)(e0+8*ty+i)*H + h0 + 8*tx + j], acc[i][j]);
}

__global__ __launch_bounds__(256) void k_tw_final(float* Tw, const float* rm){
    int i = blockIdx.x*256 + threadIdx.x;
    int h = i & (H-1);
    Tw[i] = safelog(Tw[i]) + rm[h];
}

// ---------- c_step part 1: w[e,h] = safe_log(sum_s EV[e,s]*exp(y[s,h]-mx_h)) + mx_h + Tw[e,h] ----------
__global__ __launch_bounds__(256) void k_step1(const float* y, const float* EVm,
                                               const float* Tw, float* w){
    __shared__ float EY[64][64];
    __shared__ float EVT[64][65];
    __shared__ float mx[64];
    __shared__ float red[256];
    int tid = threadIdx.x;
    int e0 = blockIdx.x*64, h0 = blockIdx.y*64;
    { int c = tid & 63, sp = tid >> 6; float m = -INFINITY;
      for (int s = sp; s < NS; s += 4) m = fmaxf(m, y[(size_t)s*H + h0 + c]);
      red[tid] = m; }
    __syncthreads();
    if (tid < 64) mx[tid] = fmaxf(fmaxf(red[tid],red[tid+64]), fmaxf(red[tid+128],red[tid+192]));
    __syncthreads();
    int tx = tid & 15, ty = tid >> 4;
    float acc[4][4] = {};
    for (int sc = 0; sc < NS; sc += 64){
        for (int idx = tid; idx < 4096; idx += 256){
            int sl = idx >> 6, c = idx & 63;
            EY[sl][c] = expf(y[(size_t)(sc+sl)*H + h0 + c] - mx[c]);
        }
        for (int idx = tid; idx < 4096; idx += 256){
            int rr = idx >> 6, sl = idx & 63;
            EVT[sl][rr] = EVm[(size_t)(e0+rr)*NS + sc + sl];
        }
        __syncthreads();
        for (int sl = 0; sl < 64; ++sl){
            float a0=EVT[sl][4*ty],a1=EVT[sl][4*ty+1],a2=EVT[sl][4*ty+2],a3=EVT[sl][4*ty+3];
            float b0=EY[sl][4*tx],b1=EY[sl][4*tx+1],b2=EY[sl][4*tx+2],b3=EY[sl][4*tx+3];
            acc[0][0]+=a0*b0; acc[0][1]+=a0*b1; acc[0][2]+=a0*b2; acc[0][3]+=a0*b3;
            acc[1][0]+=a1*b0; acc[1][1]+=a1*b1; acc[1][2]+=a1*b2; acc[1][3]+=a1*b3;
            acc[2][0]+=a2*b0; acc[2][1]+=a2*b1; acc[2][2]+=a2*b2; acc[2][3]+=a2*b3;
            acc[3][0]+=a3*b0; acc[3][1]+=a3*b1; acc[3][2]+=a3*b2; acc[3][3]+=a3*b3;
        }
        __syncthreads();
    }
    #pragma unroll
    for (int i = 0; i < 4; ++i)
        #pragma unroll
        for (int j = 0; j < 4; ++j){
            int e = e0 + 4*ty + i, h = h0 + 4*tx + j;
            w[(size_t)e*H + h] = safelog(acc[i][j]) + mx[4*tx+j] + Tw[(size_t)e*H + h];
        }
}

// ---------- c_step part 2: x[s,h] = safe_log(sum_e VE[s,e]*exp(w[e,h]-mx_h)) + mx_h ----------
__global__ __launch_bounds__(256) void k_step2(const float* w, const float* VEm, float* x){
    __shared__ float EW[128][64];
    __shared__ float VET[128][33];
    __shared__ float mx[64];
    __shared__ float red[256];
    int tid = threadIdx.x;
    int s0 = blockIdx.x*32, h0 = blockIdx.y*64;
    { int c = tid & 63, ep = tid >> 6; float m = -INFINITY;
      for (int e = ep; e < EE; e += 4) m = fmaxf(m, w[(size_t)e*H + h0 + c]);
      red[tid] = m; }
    __syncthreads();
    if (tid < 64) mx[tid] = fmaxf(fmaxf(red[tid],red[tid+64]), fmaxf(red[tid+128],red[tid+192]));
    __syncthreads();
    int tx = tid & 15, ty = tid >> 4;
    float acc[2][4] = {};
    for (int ec = 0; ec < EE; ec += 128){
        for (int idx = tid; idx < 8192; idx += 256){
            int el = idx >> 6, c = idx & 63;
            EW[el][c] = expf(w[(size_t)(ec+el)*H + h0 + c] - mx[c]);
        }
        for (int idx = tid; idx < 4096; idx += 256){
            int s = idx >> 7, el = idx & 127;
            VET[el][s] = VEm[(size_t)(s0+s)*EE + ec + el];
        }
        __syncthreads();
        for (int el = 0; el < 128; ++el){
            float a0 = VET[el][2*ty], a1 = VET[el][2*ty+1];
            float b0=EW[el][4*tx],b1=EW[el][4*tx+1],b2=EW[el][4*tx+2],b3=EW[el][4*tx+3];
            acc[0][0]+=a0*b0; acc[0][1]+=a0*b1; acc[0][2]+=a0*b2; acc[0][3]+=a0*b3;
            acc[1][0]+=a1*b0; acc[1][1]+=a1*b1; acc[1][2]+=a1*b2; acc[1][3]+=a1*b3;
        }
        __syncthreads();
    }
    #pragma unroll
    for (int i = 0; i < 2; ++i)
        #pragma unroll
        for (int j = 0; j < 4; ++j)
            x[(size_t)(s0+2*ty+i)*H + h0 + 4*tx + j] = safelog(acc[i][j]) + mx[4*tx+j];
}

// ---------- c_step part 3: C[t][s,j] = safe_log(sum_h exp(x[s,h]-rx_s)*alpha[j,h]) + rx_s ----------
__global__ __launch_bounds__(256) void k_step3(const float* x, const float* alpha, float* Ct){
    __shared__ float EXT[64][33];
    __shared__ float ALT[64][65];
    __shared__ float rx[32];
    __shared__ float red[256];
    int tid = threadIdx.x;
    int s0 = blockIdx.x*32, j0 = blockIdx.y*64;
    { int sl = tid >> 3, hp = tid & 7; float m = -INFINITY;
      for (int i = 0; i < 256; ++i) m = fmaxf(m, x[(size_t)(s0+sl)*H + hp + 8*i]);
      red[tid] = m; }
    __syncthreads();
    if (tid < 32){ float mm = red[8*tid];
        for (int qq = 1; qq < 8; ++qq) mm = fmaxf(mm, red[8*tid+qq]);
        rx[tid] = mm; }
    __syncthreads();
    int tx = tid & 15, ty = tid >> 4;
    float acc[2][4] = {};
    for (int kc = 0; kc < H; kc += 64){
        for (int idx = tid; idx < 2048; idx += 256){
            int s = idx >> 6, k = idx & 63;
            EXT[k][s] = expf(x[(size_t)(s0+s)*H + kc + k] - rx[s]);
        }
        for (int idx = tid; idx < 4096; idx += 256){
            int j = idx >> 6, k = idx & 63;
            ALT[k][j] = alpha[(size_t)(j0+j)*H + kc + k];
        }
        __syncthreads();
        for (int k = 0; k < 64; ++k){
            float a0 = EXT[k][2*ty], a1 = EXT[k][2*ty+1];
            float b0=ALT[k][4*tx],b1=ALT[k][4*tx+1],b2=ALT[k][4*tx+2],b3=ALT[k][4*tx+3];
            acc[0][0]+=a0*b0; acc[0][1]+=a0*b1; acc[0][2]+=a0*b2; acc[0][3]+=a0*b3;
            acc[1][0]+=a1*b0; acc[1][1]+=a1*b1; acc[1][2]+=a1*b2; acc[1][3]+=a1*b3;
        }
        __syncthreads();
    }
    #pragma unroll
    for (int i = 0; i < 2; ++i)
        #pragma unroll
        for (int j = 0; j < 4; ++j)
            Ct[(size_t)(s0+2*ty+i)*H + j0 + 4*tx + j] = safelog(acc[i][j]) + rx[2*ty+i];
}

// ---------- C_ranges ----------
__global__ __launch_bounds__(256) void k_cranges(const float* C, const float* rmask, float* CR){
    int col = blockIdx.x*256 + threadIdx.x;   // < NSH
    __shared__ float rmsk[RR*(TT+1)];
    for (int i = threadIdx.x; i < RR*(TT+1); i += 256) rmsk[i] = rmask[i];
    __syncthreads();
    float cv[TT+1];
    float bm = -INFINITY;
    #pragma unroll
    for (int t = 0; t <= TT; ++t){ cv[t] = C[(size_t)t*NSH + col]; bm = fmaxf(bm, cv[t]); }
    #pragma unroll
    for (int t = 0; t <= TT; ++t) cv[t] = expf(cv[t] - bm);
    for (int rr2 = 0; rr2 < RR; ++rr2){
        float s = 0.f;
        #pragma unroll
        for (int t = 0; t <= TT; ++t) s += rmsk[rr2*(TT+1)+t]*cv[t];
        CR[(size_t)rr2*NSH + col] = safelog(s) + bm;
    }
}

// ---------- Z prep: expZ, Amax_s; also expA, maxA ----------
__global__ __launch_bounds__(256) void k_zprep(const float* A, const float* CR0, float* expZ,
                                               float* AmaxS, float* expA, float* maxA){
    __shared__ float red[256];
    int tid = threadIdx.x;
    if (blockIdx.x < NS){
        int s = blockIdx.x;
        float m = -INFINITY;
        for (int h = tid; h < H; h += 256) m = fmaxf(m, A[h] + CR0[(size_t)s*H + h]);
        red[tid] = m; __syncthreads();
        for (int q = 128; q; q >>= 1){ if (tid < q) red[tid] = fmaxf(red[tid], red[tid+q]); __syncthreads(); }
        float mm = red[0];
        for (int h = tid; h < H; h += 256) expZ[(size_t)s*H + h] = expf(A[h] + CR0[(size_t)s*H + h] - mm);
        if (!tid) AmaxS[s] = mm;
    } else {
        float m = -INFINITY;
        for (int h = tid; h < H; h += 256) m = fmaxf(m, A[h]);
        red[tid] = m; __syncthreads();
        for (int q = 128; q; q >>= 1){ if (tid < q) red[tid] = fmaxf(red[tid], red[tid+q]); __syncthreads(); }
        float mm = red[0];
        for (int h = tid; h < H; h += 256) expA[h] = expf(A[h] - mm);
        if (!tid) maxA[0] = mm;
    }
}

// ---------- mask GEMM -> logmask ----------
__global__ __launch_bounds__(256) void k_mask(const float* VEm, const float* EVm, const float* Tm,
                                              const int* dstate, float* logmask){
    __shared__ float CT[64][NS+1];
    __shared__ float TL[64][65];
    int tid = threadIdx.x;
    int v0 = blockIdx.x*64;
    int d = dstate[0];
    int tx = tid & 15, ty = tid >> 4;   // v = 4*tx, s = 8*ty
    float acc[8][4] = {};
    for (int ec = 0; ec < EE; ec += 64){
        for (int idx = tid; idx < 8192; idx += 256){
            int el = idx >> 7, s = idx & 127;
            CT[el][s] = VEm[(size_t)d*EE + ec + el]*EVm[(size_t)(ec+el)*NS + s];
        }
        for (int idx = tid; idx < 4096; idx += 256){
            int el = idx >> 6, c = idx & 63;
            int v = v0 + c;
            TL[el][c] = (v < V) ? Tm[(size_t)(ec+el)*V + v] : 0.f;
        }
        __syncthreads();
        for (int el = 0; el < 64; ++el){
            float a[8], b[4];
            #pragma unroll
            for (int i = 0; i < 8; ++i) a[i] = CT[el][8*ty+i];
            #pragma unroll
            for (int j = 0; j < 4; ++j) b[j] = TL[el][4*tx+j];
            #pragma unroll
            for (int i = 0; i < 8; ++i)
                #pragma unroll
                for (int j = 0; j < 4; ++j) acc[i][j] += a[i]*b[j];
        }
        __syncthreads();
    }
    #pragma unroll
    for (int i = 0; i < 8; ++i)
        #pragma unroll
        for (int j = 0; j < 4; ++j){
            int v = v0 + 4*tx + j;
            if (v < V) logmask[(size_t)(8*ty+i)*V + v] = safelog(acc[i][j]);
        }
}

// ---------- logits: LS + logmask -> logsumexp over s ----------
__global__ __launch_bounds__(256) void k_logits(const float* expZ, const float* beta, const float* bcm,
                                                const float* AmaxS, const float* logmask, float* logits){
    __shared__ float EB[64][65];
    __shared__ float EZT[64][NS+1];
    int tid = threadIdx.x;
    int v0 = blockIdx.x*64;
    int tx = tid & 15, ty = tid >> 4;
    float acc[8][4] = {};
    for (int kc = 0; kc < H; kc += 64){
        for (int idx = tid; idx < 4096; idx += 256){
            int k = idx >> 6, c = idx & 63;
            int v = v0 + c;
            EB[k][c] = (v < V) ? expf(beta[(size_t)(kc+k)*V + v] - bcm[v]) : 0.f;
        }
        for (int idx = tid; idx < 8192; idx += 256){
            int s = idx >> 6, k = idx & 63;
            EZT[k][s] = expZ[(size_t)s*H + kc + k];
        }
        __syncthreads();
        for (int k = 0; k < 64; ++k){
            float a[8], b[4];
            #pragma unroll
            for (int i = 0; i < 8; ++i) a[i] = EZT[k][8*ty+i];
            #pragma unroll
            for (int j = 0; j < 4; ++j) b[j] = EB[k][4*tx+j];
            #pragma unroll
            for (int i = 0; i < 8; ++i)
                #pragma unroll
                for (int j = 0; j < 4; ++j) acc[i][j] += a[i]*b[j];
        }
        __syncthreads();
    }
    float* argb = &EZT[0][0];   // reuse (8256 >= 8192 floats)
    float amax[8];
    #pragma unroll
    for (int i = 0; i < 8; ++i) amax[i] = AmaxS[8*ty+i];
    #pragma unroll
    for (int i = 0; i < 8; ++i)
        #pragma unroll
        for (int j = 0; j < 4; ++j){
            int s = 8*ty + i, v = v0 + 4*tx + j;
            float arg = -INFINITY;
            if (v < V) arg = safelog(acc[i][j]) + amax[i] + bcm[v] + logmask[(size_t)s*V + v];
            argb[s*64 + 4*tx + j] = arg;
        }
    __syncthreads();
    if (tid < 64){
        int v = v0 + tid;
        if (v < V){
            float m = -INFINITY;
            for (int s = 0; s < NS; ++s) m = fmaxf(m, argb[s*64 + tid]);
            float sum = 0.f;
            for (int s = 0; s < NS; ++s) sum += expf(argb[s*64 + tid] - m);
            logits[v] = logf(sum) + m;
        }
    }
}

// ---------- logits_uncond ----------
__global__ __launch_bounds__(256) void k_luncond(const float* expA, const float* beta, const float* bcm,
                                                 const float* maxA, float* out){
    int v = blockIdx.x*256 + threadIdx.x;
    if (v >= V) return;
    float bm = bcm[v];
    float s = 0.f;
    for (int h = 0; h < H; ++h) s += expA[h]*expf(beta[(size_t)h*V + v] - bm);
    out[v] = safelog(s) + maxA[0] + bm;
}

extern "C" void kernel_launch(void* const* d_in, const int* in_sizes, int n_in,
                              void* d_out, int out_size, void* d_ws, size_t ws_size,
                              hipStream_t stream){
    const float* alpha = (const float*)d_in[0];
    const float* beta  = (const float*)d_in[1];
    const float* gamma = (const float*)d_in[2];
    const float* VEm   = (const float*)d_in[3];
    const float* EVm   = (const float*)d_in[4];
    const float* Tm    = (const float*)d_in[5];
    const float* rmask = (const float*)d_in[6];
    const int*   accept= (const int*)d_in[7];
    const int*   pre   = (const int*)d_in[8];
    const int*   suf   = (const int*)d_in[9];
    const int*   dstate= (const int*)d_in[10];
    float* out = (float*)d_out;
    float* W   = (float*)d_ws;

    const size_t VP = 50304;  // V padded to 64
    size_t o = 0;
    float* rm    = W + o; o += H;
    float* bcm   = W + o; o += VP;
    float* A0    = W + o; o += H;
    float* A1    = W + o; o += H;
    float* Bb0   = W + o; o += H;
    float* Bb1   = W + o; o += H;
    float* bpre  = W + o; o += (size_t)PP*H;
    float* bsuf  = W + o; o += (size_t)SS*H;
    float* Tw    = W + o; o += (size_t)EE*H;
    float* wbuf  = W + o; o += (size_t)EE*H;
    float* xbuf  = W + o; o += NSH;
    float* expZ  = W + o; o += NSH;
    float* AmaxS = W + o; o += 128;
    float* expA  = W + o; o += H;
    float* maxAb = W + o; o += 64;
    float* Cbuf  = W + o; o += (size_t)(TT+1)*NSH;
    float* logmask = W + o; o += (size_t)NS*VP;

    // beta reductions
    k_rowmax_beta<<<H, 256, 0, stream>>>(beta, rm);
    k_colmax_beta<<<(V+255)/256, 256, 0, stream>>>(beta, bcm);

    // T_weights
    hipMemsetAsync(Tw, 0, (size_t)EE*H*sizeof(float), stream);
    k_tw_gemm<<<dim3(64, 13), 256, 0, stream>>>(Tm, beta, rm, Tw);
    k_tw_final<<<(EE*H)/256, 256, 0, stream>>>(Tw, rm);

    // token gathers
    k_gather<<<dim3(8, PP+SS), 256, 0, stream>>>(beta, pre, suf, bpre, bsuf);

    // A scan
    k_copy<<<8, 256, 0, stream>>>(gamma, A0, H);
    {
        float* cur = A0;
        for (int i = 0; i < PP; ++i){
            float* nxt = (i & 1) ? A0 : A1;
            k_a_step<<<32, 256, 0, stream>>>(cur, bpre + (size_t)i*H, alpha, nxt);
            cur = nxt;
        }
    }
    float* Afin = A0;   // 32 steps -> ends on A0

    // B scan
    k_copy<<<8, 256, 0, stream>>>(bsuf + (size_t)(SS-1)*H, Bb0, H);
    {
        float* cur = Bb0;
        for (int i = 1; i < SS; ++i){
            float* nxt = (i & 1) ? Bb1 : Bb0;
            k_b_step<<<512, 256, 0, stream>>>(cur, bsuf + (size_t)(SS-1-i)*H, alpha, nxt);
            cur = nxt;
        }
    }
    float* Bfin = Bb1;  // 15 steps -> ends on Bb1

    // y0 -> C[0]
    k_y0<<<32, 256, 0, stream>>>(Bfin, alpha, accept, Cbuf);

    // C scan
    for (int t = 1; t <= TT; ++t){
        const float* yprev = Cbuf + (size_t)(t-1)*NSH;
        k_step1<<<dim3(8, 32), 256, 0, stream>>>(yprev, EVm, Tw, wbuf);
        k_step2<<<dim3(4, 32), 256, 0, stream>>>(wbuf, VEm, xbuf);
        k_step3<<<dim3(4, 32), 256, 0, stream>>>(xbuf, alpha, Cbuf + (size_t)t*NSH);
    }

    // C_ranges -> d_out[2V:]
    float* CR = out + 2*(size_t)V;
    k_cranges<<<NSH/256, 256, 0, stream>>>(Cbuf, rmask, CR);

    // Z prep (+ A exp)
    k_zprep<<<NS+1, 256, 0, stream>>>(Afin, CR, expZ, AmaxS, expA, maxAb);

    // mask -> logmask
    k_mask<<<(V+63)/64, 256, 0, stream>>>(VEm, EVm, Tm, dstate, logmask);

    // logits
    k_logits<<<(V+63)/64, 256, 0, stream>>>(expZ, beta, bcm, AmaxS, logmask, out);

    // logits_uncond
    k_luncond<<<(V+255)/256, 256, 0, stream>>>(expA, beta, bcm, maxAb, out + V);

    (void)in_sizes; (void)n_in; (void)out_size; (void)ws_size;
}

// Round 2
// 17004.083 us; speedup vs baseline: 1.5788x; 1.5788x over previous
//
#include <hip/hip_runtime.h>
#include <math.h>

#define H    2048
#define V    50257
#define NS   128
#define EE   512
#define TT   64
#define PP   32
#define SS   16
#define RR   16
#define NSH  (NS*H)          // 262144
#define NEGV (-1e30f)

using short8 = __attribute__((ext_vector_type(8))) short;
using f32x4  = __attribute__((ext_vector_type(4))) float;

__device__ __forceinline__ float safelog(float x){
    return x > 0.0f ? logf(fmaxf(x, 1e-38f)) : NEGV;
}

// fp32 -> bf16 round-to-nearest-even (no NaNs in this pipeline)
__device__ __forceinline__ unsigned short f2b(float f){
    union { float f; unsigned u; } x; x.f = f;
    unsigned r = x.u + 0x7fffu + ((x.u >> 16) & 1u);
    return (unsigned short)(r >> 16);
}

// ---------- reductions over beta ----------
__global__ __launch_bounds__(256) void k_rowmax_beta(const float* beta, float* rm){
    int h = blockIdx.x;
    __shared__ float red[256];
    float m = -INFINITY;
    for (int v = threadIdx.x; v < V; v += 256) m = fmaxf(m, beta[(size_t)h*V + v]);
    red[threadIdx.x] = m; __syncthreads();
    for (int s = 128; s; s >>= 1){
        if (threadIdx.x < s) red[threadIdx.x] = fmaxf(red[threadIdx.x], red[threadIdx.x+s]);
        __syncthreads();
    }
    if (!threadIdx.x) rm[h] = red[0];
}

__global__ __launch_bounds__(256) void k_colmax_beta(const float* beta, float* bcm){
    int v = blockIdx.x*256 + threadIdx.x;
    if (v >= V) return;
    float m = -INFINITY;
    for (int h = 0; h < H; ++h) m = fmaxf(m, beta[(size_t)h*V + v]);
    bcm[v] = m;
}

// ---------- gather beta columns for tokens ----------
__global__ __launch_bounds__(256) void k_gather(const float* beta, const int* pre, const int* suf,
                                                float* bpre, float* bsuf){
    int i = blockIdx.y;
    int h = blockIdx.x*256 + threadIdx.x;
    if (h >= H) return;
    if (i < PP) bpre[(size_t)i*H + h] = beta[(size_t)h*V + pre[i]];
    else        bsuf[(size_t)(i-PP)*H + h] = beta[(size_t)h*V + suf[i-PP]];
}

__global__ __launch_bounds__(256) void k_copy(const float* src, float* dst, int n){
    int i = blockIdx.x*256 + threadIdx.x;
    if (i < n) dst[i] = src[i];
}

// ---------- alpha -> bf16 ----------
__global__ __launch_bounds__(256) void k_prep_alphab(const float* a, unsigned short* ab){
    int i = blockIdx.x*1024 + threadIdx.x*4;
    float4 v = *(const float4*)(a + i);
    union { unsigned short s[4]; ushort2 u2[2]; } u;
    u.s[0] = f2b(v.x); u.s[1] = f2b(v.y); u.s[2] = f2b(v.z); u.s[3] = f2b(v.w);
    *(ushort2*)(ab + i)     = u.u2[0];
    *(ushort2*)(ab + i + 2) = u.u2[1];
}

// ---------- A scan step ----------
__global__ __launch_bounds__(256) void k_a_step(const float* yin, const float* bcol,
                                                const float* alpha, float* yout){
    __shared__ float sa[H];
    __shared__ float red[256];
    __shared__ float part[4][64];
    int tid = threadIdx.x;
    float m = -INFINITY;
    for (int j = tid; j < H; j += 256){ float a = yin[j] + bcol[j]; sa[j] = a; m = fmaxf(m, a); }
    red[tid] = m; __syncthreads();
    for (int s = 128; s; s >>= 1){ if (tid < s) red[tid] = fmaxf(red[tid], red[tid+s]); __syncthreads(); }
    float mm = red[0];
    __syncthreads();
    for (int j = tid; j < H; j += 256) sa[j] = expf(sa[j] - mm);
    __syncthreads();
    int lane = tid & 63, grp = tid >> 6;
    int j = blockIdx.x*64 + lane;
    float acc = 0.f;
    for (int h = grp*512; h < grp*512 + 512; ++h) acc += sa[h]*alpha[(size_t)h*H + j];
    part[grp][lane] = acc; __syncthreads();
    if (tid < 64){
        int jj = blockIdx.x*64 + tid;
        float s4 = part[0][tid] + part[1][tid] + part[2][tid] + part[3][tid];
        yout[jj] = safelog(s4) + mm;
    }
}

// ---------- B scan step ----------
__global__ __launch_bounds__(256) void k_b_step(const float* yin, const float* bcol,
                                                const float* alpha, float* yout){
    __shared__ float sy[H];
    __shared__ float red[256];
    int tid = threadIdx.x;
    float m = -INFINITY;
    for (int j = tid; j < H; j += 256){ float a = yin[j]; sy[j] = a; m = fmaxf(m, a); }
    red[tid] = m; __syncthreads();
    for (int s = 128; s; s >>= 1){ if (tid < s) red[tid] = fmaxf(red[tid], red[tid+s]); __syncthreads(); }
    float mm = red[0];
    __syncthreads();
    for (int j = tid; j < H; j += 256) sy[j] = expf(sy[j] - mm);
    __syncthreads();
    int lane = tid & 63, w = tid >> 6;
    int h = blockIdx.x*4 + w;
    float acc = 0.f;
    for (int j = lane; j < H; j += 64) acc += sy[j]*alpha[(size_t)h*H + j];
    for (int off = 32; off; off >>= 1) acc += __shfl_down(acc, off);
    if (!lane) yout[h] = safelog(acc) + mm + bcol[h];
}

// ---------- y0 -> C[0] ----------
__global__ __launch_bounds__(256) void k_y0(const float* B0, const float* alpha,
                                            const int* accept, float* C0){
    __shared__ float sb[H];
    __shared__ float red[256];
    __shared__ float pa[4][64], pb[4][64];
    int tid = threadIdx.x;
    float m = -INFINITY;
    for (int j = tid; j < H; j += 256){ float a = B0[j]; sb[j] = a; m = fmaxf(m, a); }
    red[tid] = m; __syncthreads();
    for (int s = 128; s; s >>= 1){ if (tid < s) red[tid] = fmaxf(red[tid], red[tid+s]); __syncthreads(); }
    float mm = red[0];
    __syncthreads();
    for (int j = tid; j < H; j += 256) sb[j] = expf(sb[j] - mm);
    __syncthreads();
    int lane = tid & 63, grp = tid >> 6;
    int j = blockIdx.x*64 + lane;
    const float4* arow = (const float4*)(alpha + (size_t)j*H);
    float sA = 0.f, sB = 0.f;
    for (int h4 = grp*128; h4 < grp*128 + 128; ++h4){
        float4 a4 = arow[h4];
        sA += sb[4*h4]*a4.x + sb[4*h4+1]*a4.y + sb[4*h4+2]*a4.z + sb[4*h4+3]*a4.w;
        sB += a4.x + a4.y + a4.z + a4.w;
    }
    pa[grp][lane] = sA; pb[grp][lane] = sB;
    __syncthreads();
    if (tid < 64){
        int jj = blockIdx.x*64 + tid;
        float SA = pa[0][tid]+pa[1][tid]+pa[2][tid]+pa[3][tid];
        float SB = pb[0][tid]+pb[1][tid]+pb[2][tid]+pb[3][tid];
        float la = safelog(SA) + mm;
        float lb = safelog(SB) + NEGV;
        for (int s = 0; s < NS; ++s) C0[(size_t)s*H + jj] = accept[s] ? la : lb;
    }
}

// ---------- T_weights: bf16 MFMA GEMM, 128x128 tile, BK=64, split-K=4 ----------
#define TW_KSPLIT 12608   // 197*64; 4 splits cover 50432 >= 50304 (V padded region zero)
__global__ __launch_bounds__(256) void k_tw_mfma(const float* Tm, const float* beta,
                                                 const float* rm, float* Twsum){
    __shared__ unsigned short As[128*72];   // +8 bf16 pad: frag reads 2-lanes/bank
    __shared__ unsigned short Bs[128*72];
    int tid = threadIdx.x;
    int mt = blockIdx.x & 3, nt = blockIdx.x >> 2;
    int e0 = mt*128, h0 = nt*128;
    int k0 = blockIdx.y * TW_KSPLIT;
    int kend = min(k0 + TW_KSPLIT, 50304);
    int wid = tid >> 6, lane = tid & 63;
    int wm = (wid >> 1)*64, wn = (wid & 1)*64;
    int lm = lane & 15, kq = lane >> 4;
    f32x4 acc[4][4];
    #pragma unroll
    for (int i = 0; i < 4; ++i)
        #pragma unroll
        for (int j = 0; j < 4; ++j) acc[i][j] = (f32x4){0.f,0.f,0.f,0.f};

    for (int kc = k0; kc < kend; kc += 64){
        #pragma unroll
        for (int q = 0; q < 4; ++q){
            int c = tid + 256*q;
            int row = c >> 3, col8 = (c & 7)*8;
            int k = kc + col8;
            // A: Tm (scalar loads: V odd => rows not 16B aligned)
            const float* ap = Tm + (size_t)(e0+row)*V + k;
            union { unsigned short s[8]; short8 v; } ua;
            #pragma unroll
            for (int i = 0; i < 8; ++i) ua.s[i] = (k + i < V) ? f2b(ap[i]) : (unsigned short)0;
            *(short8*)&As[row*72 + col8] = ua.v;
            // B: exp(beta - rm)
            float rmh = rm[h0+row];
            const float* bp = beta + (size_t)(h0+row)*V + k;
            union { unsigned short s[8]; short8 v; } ub;
            #pragma unroll
            for (int i = 0; i < 8; ++i) ub.s[i] = (k + i < V) ? f2b(expf(bp[i] - rmh)) : (unsigned short)0;
            *(short8*)&Bs[row*72 + col8] = ub.v;
        }
        __syncthreads();
        #pragma unroll
        for (int ks = 0; ks < 2; ++ks){
            short8 af[4], bf[4];
            #pragma unroll
            for (int i = 0; i < 4; ++i) af[i] = *(const short8*)&As[(wm + i*16 + lm)*72 + ks*32 + kq*8];
            #pragma unroll
            for (int j = 0; j < 4; ++j) bf[j] = *(const short8*)&Bs[(wn + j*16 + lm)*72 + ks*32 + kq*8];
            #pragma unroll
            for (int i = 0; i < 4; ++i)
                #pragma unroll
                for (int j = 0; j < 4; ++j)
                    acc[i][j] = __builtin_amdgcn_mfma_f32_16x16x32_bf16(af[i], bf[j], acc[i][j], 0, 0, 0);
        }
        __syncthreads();
    }
    // C/D layout: col = lane&15 (n), row = (lane>>4)*4 + r (m)   [m89-verified]
    #pragma unroll
    for (int i = 0; i < 4; ++i)
        #pragma unroll
        for (int j = 0; j < 4; ++j)
            #pragma unroll
            for (int r = 0; r < 4; ++r){
                int e = e0 + wm + i*16 + kq*4 + r;
                int h = h0 + wn + j*16 + lm;
                atomicAdd(&Twsum[(size_t)e*H + h], acc[i][j][r]);
            }
}

__global__ __launch_bounds__(256) void k_tw_final(float* Tw, const float* rm){
    int i = blockIdx.x*256 + threadIdx.x;
    int h = i & (H-1);
    Tw[i] = safelog(Tw[i]) + rm[h];
}

// ---------- c_step part 1 (scalar, unchanged) ----------
__global__ __launch_bounds__(256) void k_step1(const float* y, const float* EVm,
                                               const float* Tw, float* w){
    __shared__ float EY[64][64];
    __shared__ float EVT[64][65];
    __shared__ float mx[64];
    __shared__ float red[256];
    int tid = threadIdx.x;
    int e0 = blockIdx.x*64, h0 = blockIdx.y*64;
    { int c = tid & 63, sp = tid >> 6; float m = -INFINITY;
      for (int s = sp; s < NS; s += 4) m = fmaxf(m, y[(size_t)s*H + h0 + c]);
      red[tid] = m; }
    __syncthreads();
    if (tid < 64) mx[tid] = fmaxf(fmaxf(red[tid],red[tid+64]), fmaxf(red[tid+128],red[tid+192]));
    __syncthreads();
    int tx = tid & 15, ty = tid >> 4;
    float acc[4][4] = {};
    for (int sc = 0; sc < NS; sc += 64){
        for (int idx = tid; idx < 4096; idx += 256){
            int sl = idx >> 6, c = idx & 63;
            EY[sl][c] = expf(y[(size_t)(sc+sl)*H + h0 + c] - mx[c]);
        }
        for (int idx = tid; idx < 4096; idx += 256){
            int rr = idx >> 6, sl = idx & 63;
            EVT[sl][rr] = EVm[(size_t)(e0+rr)*NS + sc + sl];
        }
        __syncthreads();
        for (int sl = 0; sl < 64; ++sl){
            float a0=EVT[sl][4*ty],a1=EVT[sl][4*ty+1],a2=EVT[sl][4*ty+2],a3=EVT[sl][4*ty+3];
            float b0=EY[sl][4*tx],b1=EY[sl][4*tx+1],b2=EY[sl][4*tx+2],b3=EY[sl][4*tx+3];
            acc[0][0]+=a0*b0; acc[0][1]+=a0*b1; acc[0][2]+=a0*b2; acc[0][3]+=a0*b3;
            acc[1][0]+=a1*b0; acc[1][1]+=a1*b1; acc[1][2]+=a1*b2; acc[1][3]+=a1*b3;
            acc[2][0]+=a2*b0; acc[2][1]+=a2*b1; acc[2][2]+=a2*b2; acc[2][3]+=a2*b3;
            acc[3][0]+=a3*b0; acc[3][1]+=a3*b1; acc[3][2]+=a3*b2; acc[3][3]+=a3*b3;
        }
        __syncthreads();
    }
    #pragma unroll
    for (int i = 0; i < 4; ++i)
        #pragma unroll
        for (int j = 0; j < 4; ++j){
            int e = e0 + 4*ty + i, h = h0 + 4*tx + j;
            w[(size_t)e*H + h] = safelog(acc[i][j]) + mx[4*tx+j] + Tw[(size_t)e*H + h];
        }
}

// ---------- c_step part 2 (scalar) + per-row partial max for step3 ----------
__global__ __launch_bounds__(256) void k_step2(const float* w, const float* VEm, float* x,
                                               float* pmax){
    __shared__ float EW[128][64];
    __shared__ float VET[128][33];
    __shared__ float mx[64];
    __shared__ float red[256];
    __shared__ float pm[32][17];
    int tid = threadIdx.x;
    int s0 = blockIdx.x*32, h0 = blockIdx.y*64;
    { int c = tid & 63, ep = tid >> 6; float m = -INFINITY;
      for (int e = ep; e < EE; e += 4) m = fmaxf(m, w[(size_t)e*H + h0 + c]);
      red[tid] = m; }
    __syncthreads();
    if (tid < 64) mx[tid] = fmaxf(fmaxf(red[tid],red[tid+64]), fmaxf(red[tid+128],red[tid+192]));
    __syncthreads();
    int tx = tid & 15, ty = tid >> 4;
    float acc[2][4] = {};
    for (int ec = 0; ec < EE; ec += 128){
        for (int idx = tid; idx < 8192; idx += 256){
            int el = idx >> 6, c = idx & 63;
            EW[el][c] = expf(w[(size_t)(ec+el)*H + h0 + c] - mx[c]);
        }
        for (int idx = tid; idx < 4096; idx += 256){
            int s = idx >> 7, el = idx & 127;
            VET[el][s] = VEm[(size_t)(s0+s)*EE + ec + el];
        }
        __syncthreads();
        for (int el = 0; el < 128; ++el){
            float a0 = VET[el][2*ty], a1 = VET[el][2*ty+1];
            float b0=EW[el][4*tx],b1=EW[el][4*tx+1],b2=EW[el][4*tx+2],b3=EW[el][4*tx+3];
            acc[0][0]+=a0*b0; acc[0][1]+=a0*b1; acc[0][2]+=a0*b2; acc[0][3]+=a0*b3;
            acc[1][0]+=a1*b0; acc[1][1]+=a1*b1; acc[1][2]+=a1*b2; acc[1][3]+=a1*b3;
        }
        __syncthreads();
    }
    float lmax[2] = {-INFINITY, -INFINITY};
    #pragma unroll
    for (int i = 0; i < 2; ++i)
        #pragma unroll
        for (int j = 0; j < 4; ++j){
            float val = safelog(acc[i][j]) + mx[4*tx+j];
            x[(size_t)(s0+2*ty+i)*H + h0 + 4*tx + j] = val;
            lmax[i] = fmaxf(lmax[i], val);
        }
    pm[2*ty+0][tx] = lmax[0];
    pm[2*ty+1][tx] = lmax[1];
    __syncthreads();
    if (tid < 32){
        float m = pm[tid][0];
        for (int t2 = 1; t2 < 16; ++t2) m = fmaxf(m, pm[tid][t2]);
        pmax[(size_t)(s0 + tid)*32 + blockIdx.y] = m;
    }
}

// ---------- c_step part 3: bf16 MFMA, M=128(s) N=2048(j) K=2048(h) ----------
__global__ __launch_bounds__(256) void k_step3_mfma(const float* x, const unsigned short* alphab,
                                                    const float* pmax, float* Ct){
    __shared__ unsigned short As[128*72];
    __shared__ unsigned short Bs[128*72];
    __shared__ float rxs[128];
    int tid = threadIdx.x;
    int j0 = blockIdx.x * 128;
    if (tid < 128){
        float m = -INFINITY;
        #pragma unroll
        for (int p = 0; p < 32; ++p) m = fmaxf(m, pmax[(size_t)tid*32 + p]);
        rxs[tid] = m;
    }
    __syncthreads();
    int wid = tid >> 6, lane = tid & 63;
    int wm = (wid >> 1)*64, wn = (wid & 1)*64;
    int lm = lane & 15, kq = lane >> 4;
    f32x4 acc[4][4];
    #pragma unroll
    for (int i = 0; i < 4; ++i)
        #pragma unroll
        for (int j = 0; j < 4; ++j) acc[i][j] = (f32x4){0.f,0.f,0.f,0.f};

    for (int kc = 0; kc < H; kc += 64){
        #pragma unroll
        for (int q = 0; q < 4; ++q){
            int c = tid + 256*q;
            int row = c >> 3, col8 = (c & 7)*8;
            // A: exp(x - rx), fp32 exp (matches ref underflow pattern)
            const float4* xp = (const float4*)(x + (size_t)row*H + kc + col8);
            float4 x0 = xp[0], x1 = xp[1];
            float rx = rxs[row];
            union { unsigned short s[8]; short8 v; } ua;
            ua.s[0] = f2b(expf(x0.x - rx)); ua.s[1] = f2b(expf(x0.y - rx));
            ua.s[2] = f2b(expf(x0.z - rx)); ua.s[3] = f2b(expf(x0.w - rx));
            ua.s[4] = f2b(expf(x1.x - rx)); ua.s[5] = f2b(expf(x1.y - rx));
            ua.s[6] = f2b(expf(x1.z - rx)); ua.s[7] = f2b(expf(x1.w - rx));
            *(short8*)&As[row*72 + col8] = ua.v;
            // B: alpha bf16 (precomputed), 16B aligned
            *(uint4*)&Bs[row*72 + col8] = *(const uint4*)(alphab + (size_t)(j0+row)*H + kc + col8);
        }
        __syncthreads();
        #pragma unroll
        for (int ks = 0; ks < 2; ++ks){
            short8 af[4], bf[4];
            #pragma unroll
            for (int i = 0; i < 4; ++i) af[i] = *(const short8*)&As[(wm + i*16 + lm)*72 + ks*32 + kq*8];
            #pragma unroll
            for (int j = 0; j < 4; ++j) bf[j] = *(const short8*)&Bs[(wn + j*16 + lm)*72 + ks*32 + kq*8];
            #pragma unroll
            for (int i = 0; i < 4; ++i)
                #pragma unroll
                for (int j = 0; j < 4; ++j)
                    acc[i][j] = __builtin_amdgcn_mfma_f32_16x16x32_bf16(af[i], bf[j], acc[i][j], 0, 0, 0);
        }
        __syncthreads();
    }
    #pragma unroll
    for (int i = 0; i < 4; ++i)
        #pragma unroll
        for (int j = 0; j < 4; ++j)
            #pragma unroll
            for (int r = 0; r < 4; ++r){
                int s = wm + i*16 + kq*4 + r;
                int jc = j0 + wn + j*16 + lm;
                Ct[(size_t)s*H + jc] = safelog(acc[i][j][r]) + rxs[s];
            }
}

// ---------- C_ranges ----------
__global__ __launch_bounds__(256) void k_cranges(const float* C, const float* rmask, float* CR){
    int col = blockIdx.x*256 + threadIdx.x;   // < NSH
    __shared__ float rmsk[RR*(TT+1)];
    for (int i = threadIdx.x; i < RR*(TT+1); i += 256) rmsk[i] = rmask[i];
    __syncthreads();
    float cv[TT+1];
    float bm = -INFINITY;
    #pragma unroll
    for (int t = 0; t <= TT; ++t){ cv[t] = C[(size_t)t*NSH + col]; bm = fmaxf(bm, cv[t]); }
    #pragma unroll
    for (int t = 0; t <= TT; ++t) cv[t] = expf(cv[t] - bm);
    for (int rr2 = 0; rr2 < RR; ++rr2){
        float s = 0.f;
        #pragma unroll
        for (int t = 0; t <= TT; ++t) s += rmsk[rr2*(TT+1)+t]*cv[t];
        CR[(size_t)rr2*NSH + col] = safelog(s) + bm;
    }
}

// ---------- Z prep ----------
__global__ __launch_bounds__(256) void k_zprep(const float* A, const float* CR0, float* expZ,
                                               float* AmaxS, float* expA, float* maxA){
    __shared__ float red[256];
    int tid = threadIdx.x;
    if (blockIdx.x < NS){
        int s = blockIdx.x;
        float m = -INFINITY;
        for (int h = tid; h < H; h += 256) m = fmaxf(m, A[h] + CR0[(size_t)s*H + h]);
        red[tid] = m; __syncthreads();
        for (int q = 128; q; q >>= 1){ if (tid < q) red[tid] = fmaxf(red[tid], red[tid+q]); __syncthreads(); }
        float mm = red[0];
        for (int h = tid; h < H; h += 256) expZ[(size_t)s*H + h] = expf(A[h] + CR0[(size_t)s*H + h] - mm);
        if (!tid) AmaxS[s] = mm;
    } else {
        float m = -INFINITY;
        for (int h = tid; h < H; h += 256) m = fmaxf(m, A[h]);
        red[tid] = m; __syncthreads();
        for (int q = 128; q; q >>= 1){ if (tid < q) red[tid] = fmaxf(red[tid], red[tid+q]); __syncthreads(); }
        float mm = red[0];
        for (int h = tid; h < H; h += 256) expA[h] = expf(A[h] - mm);
        if (!tid) maxA[0] = mm;
    }
}

// ---------- mask GEMM -> logmask ----------
__global__ __launch_bounds__(256) void k_mask(const float* VEm, const float* EVm, const float* Tm,
                                              const int* dstate, float* logmask){
    __shared__ float CT[64][NS+1];
    __shared__ float TL[64][65];
    int tid = threadIdx.x;
    int v0 = blockIdx.x*64;
    int d = dstate[0];
    int tx = tid & 15, ty = tid >> 4;
    float acc[8][4] = {};
    for (int ec = 0; ec < EE; ec += 64){
        for (int idx = tid; idx < 8192; idx += 256){
            int el = idx >> 7, s = idx & 127;
            CT[el][s] = VEm[(size_t)d*EE + ec + el]*EVm[(size_t)(ec+el)*NS + s];
        }
        for (int idx = tid; idx < 4096; idx += 256){
            int el = idx >> 6, c = idx & 63;
            int v = v0 + c;
            TL[el][c] = (v < V) ? Tm[(size_t)(ec+el)*V + v] : 0.f;
        }
        __syncthreads();
        for (int el = 0; el < 64; ++el){
            float a[8], b[4];
            #pragma unroll
            for (int i = 0; i < 8; ++i) a[i] = CT[el][8*ty+i];
            #pragma unroll
            for (int j = 0; j < 4; ++j) b[j] = TL[el][4*tx+j];
            #pragma unroll
            for (int i = 0; i < 8; ++i)
                #pragma unroll
                for (int j = 0; j < 4; ++j) acc[i][j] += a[i]*b[j];
        }
        __syncthreads();
    }
    #pragma unroll
    for (int i = 0; i < 8; ++i)
        #pragma unroll
        for (int j = 0; j < 4; ++j){
            int v = v0 + 4*tx + j;
            if (v < V) logmask[(size_t)(8*ty+i)*V + v] = safelog(acc[i][j]);
        }
}

// ---------- logits ----------
__global__ __launch_bounds__(256) void k_logits(const float* expZ, const float* beta, const float* bcm,
                                                const float* AmaxS, const float* logmask, float* logits){
    __shared__ float EB[64][65];
    __shared__ float EZT[64][NS+1];
    int tid = threadIdx.x;
    int v0 = blockIdx.x*64;
    int tx = tid & 15, ty = tid >> 4;
    float acc[8][4] = {};
    for (int kc = 0; kc < H; kc += 64){
        for (int idx = tid; idx < 4096; idx += 256){
            int k = idx >> 6, c = idx & 63;
            int v = v0 + c;
            EB[k][c] = (v < V) ? expf(beta[(size_t)(kc+k)*V + v] - bcm[v]) : 0.f;
        }
        for (int idx = tid; idx < 8192; idx += 256){
            int s = idx >> 6, k = idx & 63;
            EZT[k][s] = expZ[(size_t)s*H + kc + k];
        }
        __syncthreads();
        for (int k = 0; k < 64; ++k){
            float a[8], b[4];
            #pragma unroll
            for (int i = 0; i < 8; ++i) a[i] = EZT[k][8*ty+i];
            #pragma unroll
            for (int j = 0; j < 4; ++j) b[j] = EB[k][4*tx+j];
            #pragma unroll
            for (int i = 0; i < 8; ++i)
                #pragma unroll
                for (int j = 0; j < 4; ++j) acc[i][j] += a[i]*b[j];
        }
        __syncthreads();
    }
    float* argb = &EZT[0][0];
    float amax[8];
    #pragma unroll
    for (int i = 0; i < 8; ++i) amax[i] = AmaxS[8*ty+i];
    #pragma unroll
    for (int i = 0; i < 8; ++i)
        #pragma unroll
        for (int j = 0; j < 4; ++j){
            int s = 8*ty + i, v = v0 + 4*tx + j;
            float arg = -INFINITY;
            if (v < V) arg = safelog(acc[i][j]) + amax[i] + bcm[v] + logmask[(size_t)s*V + v];
            argb[s*64 + 4*tx + j] = arg;
        }
    __syncthreads();
    if (tid < 64){
        int v = v0 + tid;
        if (v < V){
            float m = -INFINITY;
            for (int s = 0; s < NS; ++s) m = fmaxf(m, argb[s*64 + tid]);
            float sum = 0.f;
            for (int s = 0; s < NS; ++s) sum += expf(argb[s*64 + tid] - m);
            logits[v] = logf(sum) + m;
        }
    }
}

// ---------- logits_uncond ----------
__global__ __launch_bounds__(256) void k_luncond(const float* expA, const float* beta, const float* bcm,
                                                 const float* maxA, float* out){
    int v = blockIdx.x*256 + threadIdx.x;
    if (v >= V) return;
    float bm = bcm[v];
    float s = 0.f;
    for (int h = 0; h < H; ++h) s += expA[h]*expf(beta[(size_t)h*V + v] - bm);
    out[v] = safelog(s) + maxA[0] + bm;
}

extern "C" void kernel_launch(void* const* d_in, const int* in_sizes, int n_in,
                              void* d_out, int out_size, void* d_ws, size_t ws_size,
                              hipStream_t stream){
    const float* alpha = (const float*)d_in[0];
    const float* beta  = (const float*)d_in[1];
    const float* gamma = (const float*)d_in[2];
    const float* VEm   = (const float*)d_in[3];
    const float* EVm   = (const float*)d_in[4];
    const float* Tm    = (const float*)d_in[5];
    const float* rmask = (const float*)d_in[6];
    const int*   accept= (const int*)d_in[7];
    const int*   pre   = (const int*)d_in[8];
    const int*   suf   = (const int*)d_in[9];
    const int*   dstate= (const int*)d_in[10];
    float* out = (float*)d_out;
    float* W   = (float*)d_ws;

    const size_t VP = 50304;  // V padded to 64
    size_t o = 0;
    float* rm    = W + o; o += H;
    float* bcm   = W + o; o += VP;
    float* A0    = W + o; o += H;
    float* A1    = W + o; o += H;
    float* Bb0   = W + o; o += H;
    float* Bb1   = W + o; o += H;
    float* bpre  = W + o; o += (size_t)PP*H;
    float* bsuf  = W + o; o += (size_t)SS*H;
    float* Tw    = W + o; o += (size_t)EE*H;
    float* wbuf  = W + o; o += (size_t)EE*H;
    float* xbuf  = W + o; o += NSH;
    float* expZ  = W + o; o += NSH;
    float* AmaxS = W + o; o += 128;
    float* expA  = W + o; o += H;
    float* maxAb = W + o; o += 64;
    float* pmax  = W + o; o += 4096;
    unsigned short* alphab = (unsigned short*)(W + o); o += ((size_t)H*H)/2;
    float* Cbuf  = W + o; o += (size_t)(TT+1)*NSH;
    float* logmask = W + o; o += (size_t)NS*VP;

    // beta reductions + bf16 alpha
    k_rowmax_beta<<<H, 256, 0, stream>>>(beta, rm);
    k_colmax_beta<<<(V+255)/256, 256, 0, stream>>>(beta, bcm);
    k_prep_alphab<<<(H*H)/1024, 256, 0, stream>>>(alpha, alphab);

    // T_weights (MFMA)
    hipMemsetAsync(Tw, 0, (size_t)EE*H*sizeof(float), stream);
    k_tw_mfma<<<dim3(64, 4), 256, 0, stream>>>(Tm, beta, rm, Tw);
    k_tw_final<<<(EE*H)/256, 256, 0, stream>>>(Tw, rm);

    // token gathers
    k_gather<<<dim3(8, PP+SS), 256, 0, stream>>>(beta, pre, suf, bpre, bsuf);

    // A scan
    k_copy<<<8, 256, 0, stream>>>(gamma, A0, H);
    {
        float* cur = A0;
        for (int i = 0; i < PP; ++i){
            float* nxt = (i & 1) ? A0 : A1;
            k_a_step<<<32, 256, 0, stream>>>(cur, bpre + (size_t)i*H, alpha, nxt);
            cur = nxt;
        }
    }
    float* Afin = A0;

    // B scan
    k_copy<<<8, 256, 0, stream>>>(bsuf + (size_t)(SS-1)*H, Bb0, H);
    {
        float* cur = Bb0;
        for (int i = 1; i < SS; ++i){
            float* nxt = (i & 1) ? Bb1 : Bb0;
            k_b_step<<<512, 256, 0, stream>>>(cur, bsuf + (size_t)(SS-1-i)*H, alpha, nxt);
            cur = nxt;
        }
    }
    float* Bfin = Bb1;

    // y0 -> C[0]
    k_y0<<<32, 256, 0, stream>>>(Bfin, alpha, accept, Cbuf);

    // C scan
    for (int t = 1; t <= TT; ++t){
        const float* yprev = Cbuf + (size_t)(t-1)*NSH;
        k_step1<<<dim3(8, 32), 256, 0, stream>>>(yprev, EVm, Tw, wbuf);
        k_step2<<<dim3(4, 32), 256, 0, stream>>>(wbuf, VEm, xbuf, pmax);
        k_step3_mfma<<<16, 256, 0, stream>>>(xbuf, alphab, pmax, Cbuf + (size_t)t*NSH);
    }

    // C_ranges -> d_out[2V:]
    float* CR = out + 2*(size_t)V;
    k_cranges<<<NSH/256, 256, 0, stream>>>(Cbuf, rmask, CR);

    // Z prep
    k_zprep<<<NS+1, 256, 0, stream>>>(Afin, CR, expZ, AmaxS, expA, maxAb);

    // mask -> logmask
    k_mask<<<(V+63)/64, 256, 0, stream>>>(VEm, EVm, Tm, dstate, logmask);

    // logits
    k_logits<<<(V+63)/64, 256, 0, stream>>>(expZ, beta, bcm, AmaxS, logmask, out);

    // logits_uncond
    k_luncond<<<(V+255)/256, 256, 0, stream>>>(expA, beta, bcm, maxAb, out + V);

    (void)in_sizes; (void)n_in; (void)out_size; (void)ws_size;
}